// Round 7
// baseline (10.639 us; speedup 1.0000x reference)
//
#include <hip/hip_runtime.h>
#include <math.h>

#define NT 576   // 9 waves: waves 0..8 build (one w each), t<512 evals

// Fully factorized: <Z_w>(x) = sum_{jkl} T_w[j,k,l] q0[j] q1[k] q2[l],
// q_i = (cos^2, cos*sin, sin^2)(x_i/2). T theta-only.
// Build is 2-barrier: phase 1 builds small tables; then each wave w
// computes W_w -> M_w -> S_w -> T-row wave-synchronously in its own
// private LDS slice (same-wave ds ops are in-order; no barriers).
__global__ __launch_bounds__(NT)
void qpkpd_kernel(const float* __restrict__ cov,
                  const float* __restrict__ dose,
                  const float* __restrict__ theta,
                  float* __restrict__ out, int B)
{
    __shared__ float  sA0T[96];          // alpha0 transposed [c][12] padded
    __shared__ float2 sCS1[72];          // (cos,sin) alpha1 [w][c']
    __shared__ float2 sV0T[64];          // [c*8+r] = V0[r][c]
    __shared__ float2 sV1T[64];          // [c*8+cp] = V1[cp][c]
    __shared__ float2 sG2[576];          // W_w  [w*64 + r*8 + c]
    __shared__ float2 sMT[576];          // M^T  [w*64 + c*8 + k1]
    __shared__ float  sS[576];           // S_w  [w*64 + r*8 + c]
    __shared__ float  sTf[252];          // T[9][28] padded

    const int t  = threadIdx.x;
    const int wv = t >> 6;               // wave id = wire w (0..8)
    const int p  = t & 63;

    // ---- prologue: eval threads issue their loads before any barrier ----
    float2 xy = make_float2(0.f, 0.f);
    float  xd = 0.f;
    int b = blockIdx.x * 512 + t;
    bool ev = (t < 512) && (b < B);
    if (ev) {
        xy = ((const float2*)cov)[b];
        xd = dose[b];
    }

    // ---- phase 1: V0/V1 (t<128) + alpha tables (128<=t<200) ----
    if (t < 128) {
        int l = t >> 6, rc = t & 63;
        int r = rc >> 3, c = rc & 7;
        float tr = 1.f, ti = 0.f;
        #pragma unroll
        for (int q = 0; q < 3; ++q) {
            float h0 = 0.5f*theta[l*9 + q*3 + 0];
            float h1 = 0.5f*theta[l*9 + q*3 + 1];
            float h2 = 0.5f*theta[l*9 + q*3 + 2];
            float s0=__sinf(h0), c0=__cosf(h0);
            float s1=__sinf(h1), c1=__cosf(h1);
            float s2=__sinf(h2), c2=__cosf(h2);
            int a = (r >> (2-q)) & 1, bb = (c >> (2-q)) & 1;
            // E = RZ(e2)*RY(e1)*RX(e0), entry [a][bb]
            float rab  = (a==bb) ? c1 : (a ? s1 : -s1);
            float ra1b = (a!=bb) ? c1 : (a ? s1 : -s1);
            float mr = rab*c0, mi = -ra1b*s0;
            float sa = a ? -1.f : 1.f;
            float er = mr*c2 + sa*mi*s2;
            float ei = mi*c2 - sa*mr*s2;
            float nr = tr*er - ti*ei;
            ti = tr*ei + ti*er;
            tr = nr;
        }
        int rb0=(r>>2)&1, rb1=(r>>1)&1, rb2=r&1;
        int nb1 = rb1 ^ rb0, nb2 = rb2 ^ nb1, nb0 = rb0 ^ nb2;  // CNOT chain
        int pr = (nb0<<2)|(nb1<<1)|nb2;
        if (l == 0) sV0T[c*8 + pr] = make_float2(tr, ti);
        else        sV1T[c*8 + pr] = make_float2(tr, ti);
    } else if (t < 200) {
        int idx = t - 128;
        int w = idx >> 3, c = idx & 7;
        float b0 = (float)((c>>2)&1), b1 = (float)((c>>1)&1), b2 = (float)(c&1);
        float a0, a1;
        if (w < 5) {
            a0 = theta[72 + w] + b0*theta[18 + w] + b1*theta[23 + w] + b2*theta[28 + w];
            a1 = theta[77 + w] + b0*theta[33 + w] + b1*theta[38 + w] + b2*theta[43 + w];
        } else {
            int k = w - 5;
            a0 = theta[82 + k] + b0*theta[48 + k] + b1*theta[52 + k] + b2*theta[56 + k];
            a1 = theta[86 + k] + b0*theta[60 + k] + b1*theta[64 + k] + b2*theta[68 + k];
        }
        sA0T[c*12 + w] = a0;
        sCS1[idx] = make_float2(__cosf(a1), __sinf(a1));
    }
    __syncthreads();

    // ---- wave-local pipeline: wave w owns its w-slice end-to-end ----
    {
        const int w = wv;
        const int r = p >> 3, c = p & 7;

        // A0 columns r and c (12-padded rows -> 3 float4 each)
        const float4* a4r = (const float4*)(&sA0T[r*12]);
        const float4* a4c = (const float4*)(&sA0T[c*12]);
        float4 A, Bv;
        float ar_[9], ac_[9];
        A = a4r[0]; ar_[0]=A.x; ar_[1]=A.y; ar_[2]=A.z; ar_[3]=A.w;
        A = a4r[1]; ar_[4]=A.x; ar_[5]=A.y; ar_[6]=A.z; ar_[7]=A.w;
        ar_[8] = sA0T[r*12 + 8];
        Bv = a4c[0]; ac_[0]=Bv.x; ac_[1]=Bv.y; ac_[2]=Bv.z; ac_[3]=Bv.w;
        Bv = a4c[1]; ac_[4]=Bv.x; ac_[5]=Bv.y; ac_[6]=Bv.z; ac_[7]=Bv.w;
        ac_[8] = sA0T[c*12 + 8];

        float C = 1.f, sh = 0.f;
        #pragma unroll
        for (int v = 0; v < 9; ++v) {
            if (v == w) sh = 0.5f*(ar_[v] + ac_[v]);
            else        C *= __cosf(0.5f*(ar_[v] - ac_[v]));
        }
        float P = C*__cosf(sh), Q = C*__sinf(sh);

        // K,L: V1 columns r,c (contiguous float2 rows of sV1T)
        const float4* v1r = (const float4*)(&sV1T[r*8]);
        const float4* v1c = (const float4*)(&sV1T[c*8]);
        const float4* cs4 = (const float4*)(&sCS1[w*8]);
        float Kr=0.f, Ki=0.f, Lr=0.f, Li=0.f;
        #pragma unroll
        for (int i = 0; i < 4; ++i) {
            float4 a = v1r[i];     // V1[2i][r], V1[2i+1][r]
            float4 bq = v1c[i];    // V1[2i][c], V1[2i+1][c]
            float4 cs = cs4[i];    // (cos,sin) for cp=2i, 2i+1
            float pr0 = a.x*bq.x + a.y*bq.y, pi0 = a.y*bq.x - a.x*bq.y;
            float pr1 = a.z*bq.z + a.w*bq.w, pi1 = a.w*bq.z - a.z*bq.w;
            Kr += cs.x*pr0 + cs.z*pr1;  Ki += cs.x*pi0 + cs.z*pi1;
            Lr += cs.y*pr0 + cs.w*pr1;  Li += cs.y*pi0 + cs.w*pi1;
        }
        sG2[w*64 + p] = make_float2(P*Kr - Q*Lr, P*Ki - Q*Li);   // W_w[r][c]

        // M[r][c] = sum_k W[r][k] * conj(V0[k][c])  (same-wave LDS, in-order)
        const float4* gp = (const float4*)(&sG2[w*64 + r*8]);
        const float4* vc = (const float4*)(&sV0T[c*8]);
        float mr = 0.f, mi = 0.f;
        #pragma unroll
        for (int i = 0; i < 4; ++i) {
            float4 g = gp[i];     // (Wr,Wi,Wr,Wi) k=2i,2i+1
            float4 v = vc[i];     // (vr,vi,vr,vi)
            mr += g.x*v.x + g.y*v.y + g.z*v.z + g.w*v.w;
            mi += g.y*v.x - g.x*v.y + g.w*v.z - g.z*v.w;
        }
        sMT[w*64 + c*8 + r] = make_float2(mr, mi);               // M^T

        // S[r][c] = Re sum_k V0[k][r] * M[k][c]
        const float4* vr4 = (const float4*)(&sV0T[r*8]);
        const float4* mp  = (const float4*)(&sMT[w*64 + c*8]);
        float s = 0.f;
        #pragma unroll
        for (int i = 0; i < 4; ++i) {
            float4 v = vr4[i], m = mp[i];
            s += v.x*m.x - v.y*m.y + v.z*m.z - v.w*m.w;
        }
        sS[w*64 + p] = s;

        // T-row aggregation (lanes p<27 of this wave; same-wave LDS)
        if (p < 27) {
            const float sc[9] = {2.45f, 9.5f, 45.0f, 0.975f, 4.95f,
                                 0.495f, 2.45f, 24.5f, 0.975f};  // 0.5*(hi-lo)
            int j = p / 9, k = (p / 3) % 3, l = p % 3;
            float acc = 0.f;
            #pragma unroll
            for (int aj = 0; aj < 2; ++aj) {
                bool vj = (j == 1) || (aj == 0);
                int a0b = (j == 2) || (j == 1 && aj == 1);
                int b0b = (j == 2) || (j == 1 && aj == 0);
                #pragma unroll
                for (int ak = 0; ak < 2; ++ak) {
                    bool vk = (k == 1) || (ak == 0);
                    int a1b = (k == 2) || (k == 1 && ak == 1);
                    int b1b = (k == 2) || (k == 1 && ak == 0);
                    #pragma unroll
                    for (int al = 0; al < 2; ++al) {
                        bool vl = (l == 1) || (al == 0);
                        int a2b = (l == 2) || (l == 1 && al == 1);
                        int b2b = (l == 2) || (l == 1 && al == 0);
                        if (vj && vk && vl) {
                            int rr = a0b*4 + a1b*2 + a2b;
                            int cc = b0b*4 + b1b*2 + b2b;
                            acc += sS[w*64 + rr*8 + cc];
                        }
                    }
                }
            }
            sTf[w*28 + p] = acc * sc[w];
        }
        if (p == 27) sTf[w*28 + 27] = 0.f;   // pad
    }
    __syncthreads();

    // ---- eval: 1 thread = 1 sample ----
    if (ev) {
        float h0 = 0.5f*xy.x, h1 = 0.5f*xy.y, h2 = 0.5f*xd;
        float s0=__sinf(h0), c0=__cosf(h0);
        float s1=__sinf(h1), c1=__cosf(h1);
        float s2=__sinf(h2), c2=__cosf(h2);
        float q0[3] = {c0*c0, c0*s0, s0*s0};
        float q1[3] = {c1*c1, c1*s1, s1*s1};
        float q2[3] = {c2*c2, c2*s2, s2*s2};

        float4 m4[7];
        float* m = (float*)m4;
        #pragma unroll
        for (int j = 0; j < 3; ++j) {
            #pragma unroll
            for (int k = 0; k < 3; ++k) {
                float rr = q0[j]*q1[k];
                #pragma unroll
                for (int l = 0; l < 3; ++l)
                    m[j*9 + k*3 + l] = rr*q2[l];
            }
        }
        m[27] = 0.f;

        const float off[9] = {2.55f, 10.5f, 55.0f, 1.025f, 5.05f,
                              0.505f, 2.55f, 25.5f, 1.025f};  // lo + 0.5*(hi-lo)
        #pragma unroll
        for (int w = 0; w < 9; ++w) {
            float g = off[w];
            const float4* tp = (const float4*)(&sTf[w*28]);
            #pragma unroll
            for (int i = 0; i < 7; ++i) {
                float4 tt = tp[i];
                float4 mm = m4[i];
                g += tt.x*mm.x + tt.y*mm.y + tt.z*mm.z + tt.w*mm.w;
            }
            if (w < 5) out[b*5 + w] = g;
            else       out[B*5 + b*4 + (w-5)] = g;
        }
    }
}

extern "C" void kernel_launch(void* const* d_in, const int* in_sizes, int n_in,
                              void* d_out, int out_size, void* d_ws, size_t ws_size,
                              hipStream_t stream)
{
    // d_in[0]: subject_ids (int32, B) — unused
    // d_in[1]: covariates  (f32, B*2)
    // d_in[2]: dose_intensities (f32, B)
    // d_in[3]: theta (f32, 90)
    const float* cov   = (const float*)d_in[1];
    const float* dose  = (const float*)d_in[2];
    const float* theta = (const float*)d_in[3];
    float* out = (float*)d_out;
    const int B = in_sizes[2];   // 512

    int grid = (B + 511) / 512;  // 1 block for B=512
    qpkpd_kernel<<<grid, NT, 0, stream>>>(cov, dose, theta, out, B);
}